// Round 9
// baseline (355.935 us; speedup 1.0000x reference)
//
#include <hip/hip_runtime.h>

namespace {
constexpr int TT = 128;

__device__ __forceinline__ float rdlane(float v, int l) {
  return __int_as_float(__builtin_amdgcn_readlane(__float_as_int(v), l));
}

__device__ __forceinline__ void bsync() {
  // 512-thread barrier WITHOUT vmcnt drain: global prefetches stay in flight.
  asm volatile("s_waitcnt lgkmcnt(0)" ::: "memory");
  __builtin_amdgcn_s_barrier();
  asm volatile("" ::: "memory");
  __builtin_amdgcn_sched_barrier(0);
}

// Two chains per block (P = waves 0-3, Q = waves 4-7), antiphase-scheduled so
// every barrier interval pairs one chain's 1-wave GJ slot with the other
// chain's full-width A/B phase. LDS = 2 x 80.6KB = 157KB (1 block/CU).
__global__ __launch_bounds__(512)
void lqr_kernel(const float* __restrict__ Qg, const float* __restrict__ pg,
                const float* __restrict__ Fg, const float* __restrict__ cg,
                const float* __restrict__ x0g, float* __restrict__ out)
{
  // Quad-XOR-swizzled tiles: element (row, n) at row*S + ((n>>2 ^ ((row>>2)&3))<<2) + (n&3)
  __shared__ __align__(16) float VT[2][16][20];
  __shared__ __align__(16) float vv[2][16];
  __shared__ __align__(16) float FTxd[2][2][25][20]; // [chain][dbuf]
  __shared__ __align__(16) float WTx[2][25][20];
  __shared__ __align__(16) float QhT[2][25][36];
  __shared__ __align__(16) float Ks[2][TT][16][8];   // Ks[c][t][j][cc] = K[cc][j]
  __shared__ __align__(16) float ksv[2][TT][8];

  const int tid  = threadIdx.x;
  const int cid  = tid >> 8;        // chain: 0 = P, 1 = Q
  const int ctid = tid & 255;       // chain-local tid
  const int lane = ctid & 63;
  const int cwv  = ctid >> 6;       // chain-local wave 0..3
  const int b2   = blockIdx.x * 2 + cid;
  const size_t bt0 = (size_t)b2 * TT;

  const int jl = ctid & 31;         // per-lane column index (valid <25 / <24)
  const int g  = ctid >> 5;         // 0..7, uniform per half-wave

  // zero V (320 floats) + v per chain
  for (int e = ctid; e < 320; e += 256) (&VT[cid][0][0])[e] = 0.f;
  if (ctid < 16) vv[cid][ctid] = 0.f;

  // ---- F/c staging: unit u = ctid < 100 (chain waves 0-1 only)
  const int  fj   = ctid >> 2, fk = ctid & 3;
  const bool fact = (ctid < 100);
  const int  fsw  = (fj < 24) ? ((fj >> 2) & 3) : 2;
  float Fr4[4] = {0.f, 0.f, 0.f, 0.f};
  float qreg[3] = {0.f, 0.f, 0.f}, qreg3 = 0.f;
  float fr[16];                     // F column cache, set in A, used in B

  auto loadF = [&](int t) {
    if (fact) {
      if (fj < 24) {
        const float* Fs = Fg + (bt0 + t) * 384 + fj;
        #pragma unroll
        for (int m = 0; m < 4; ++m) Fr4[m] = Fs[(4 * fk + m) * 24];
      } else {
        const float* cs = cg + (bt0 + t) * 16 + 4 * fk;
        #pragma unroll
        for (int m = 0; m < 4; ++m) Fr4[m] = cs[m];
      }
    }
  };
  auto commitF = [&](int buf) {
    if (fact) {
      float* dst = &FTxd[cid][buf][fj][(fk ^ fsw) << 2];
      *(float4*)dst = make_float4(Fr4[0], Fr4[1], Fr4[2], Fr4[3]);
    }
  };
  auto loadQ = [&](int t) {
    if (jl < 24) {
      const float* Qs = Qg + (bt0 + t) * 576;
      #pragma unroll
      for (int r = 0; r < 3; ++r) qreg[r] = Qs[(3 * g + r) * 24 + jl]; // Q sym
      if (g == 7) qreg3 = pg[(bt0 + t) * 24 + jl];
    }
  };

  // Phase A: WTx[j][m] = sum_n V[m][n] * F[n][j]  (+v for j==24 -> z)
  auto phaseA = [&](int t) {
    const float* Fb = &FTxd[cid][t & 1][0][0];
    if (jl < 25) {
      const int sj = (jl >> 2) & 3;
      const float* fb = Fb + jl * 20;
      #pragma unroll
      for (int q = 0; q < 4; ++q) {
        float4 v4 = *(const float4*)(fb + ((q ^ sj) << 2));
        fr[4*q+0] = v4.x; fr[4*q+1] = v4.y; fr[4*q+2] = v4.z; fr[4*q+3] = v4.w;
      }
      const int m0 = 2 * g, m1 = m0 + 1;
      float acc0 = (jl == 24) ? vv[cid][m0] : 0.f;
      float acc1 = (jl == 24) ? vv[cid][m1] : 0.f;
      #pragma unroll
      for (int q = 0; q < 4; ++q) {
        float4 a0 = *(const float4*)(&VT[cid][m0][4*q]);  // broadcast/half-wave
        float4 a1 = *(const float4*)(&VT[cid][m1][4*q]);
        acc0 = fmaf(a0.x, fr[4*q+0], acc0); acc0 = fmaf(a0.y, fr[4*q+1], acc0);
        acc0 = fmaf(a0.z, fr[4*q+2], acc0); acc0 = fmaf(a0.w, fr[4*q+3], acc0);
        acc1 = fmaf(a1.x, fr[4*q+0], acc1); acc1 = fmaf(a1.y, fr[4*q+1], acc1);
        acc1 = fmaf(a1.z, fr[4*q+2], acc1); acc1 = fmaf(a1.w, fr[4*q+3], acc1);
      }
      float* wb = &WTx[cid][0][0] + jl * 20;
      *(float2*)(wb + ((((g >> 1) ^ sj) << 2) + (m0 & 3))) = make_float2(acc0, acc1);
    }
  };

  // Phase B: QhT[c][i] = Qsrc + sum_m F[m][i] * W[m][c]   (i = jl)
  auto phaseB = [&](int t) {
    if (jl < 24) {
      #pragma unroll
      for (int r = 0; r < 3; ++r) {
        const int c = 3 * g + r;
        const int sc = (c >> 2) & 3;
        const float* wb = &WTx[cid][0][0] + c * 20;   // broadcast per half-wave
        float acc = qreg[r];
        #pragma unroll
        for (int q = 0; q < 4; ++q) {
          float4 w4 = *(const float4*)(wb + ((q ^ sc) << 2));
          acc = fmaf(w4.x, fr[4*q+0], acc); acc = fmaf(w4.y, fr[4*q+1], acc);
          acc = fmaf(w4.z, fr[4*q+2], acc); acc = fmaf(w4.w, fr[4*q+3], acc);
        }
        float* qb = &QhT[cid][0][0] + c * 36;
        qb[(((jl >> 2) ^ sc) << 2) + (jl & 3)] = acc;
      }
      if (g == 7) {                               // qh row (c==24), s=2
        const float* wb = &WTx[cid][0][0] + 24 * 20;
        float acc = qreg3;
        #pragma unroll
        for (int q = 0; q < 4; ++q) {
          float4 w4 = *(const float4*)(wb + ((q ^ 2) << 2));
          acc = fmaf(w4.x, fr[4*q+0], acc); acc = fmaf(w4.y, fr[4*q+1], acc);
          acc = fmaf(w4.z, fr[4*q+2], acc); acc = fmaf(w4.w, fr[4*q+3], acc);
        }
        float* qb = &QhT[cid][0][0] + 24 * 36;
        qb[(((jl >> 2) ^ 2) << 2) + (jl & 3)] = acc;
      }
    }
    if (t > 0) loadQ(t - 1);
  };

  // GJ + gains + V-update on chain wave 2+(tg&1) (disjoint from staging waves 0-1)
  auto phaseG = [&](int tg) {
    if (cwv != 2 + (tg & 1)) return;
    __builtin_amdgcn_s_setprio(1);
    // lanes 0..7 = Quu cols, 8..23 = Qux cols (x-col j at lane 8+j), 24 = qu
    const int cl = (lane < 25) ? lane : 0;
    const int row = (cl < 8) ? (16 + cl) : ((cl < 24) ? (cl - 8) : 24);
    const int s = (row >> 2) & 3;
    const float* base = &QhT[cid][0][0] + row * 36;
    float a_[8];
    {
      float4 x0v = *(const float4*)(base + ((4 ^ s) << 2));
      float4 x1v = *(const float4*)(base + ((5 ^ s) << 2));
      a_[0]=x0v.x; a_[1]=x0v.y; a_[2]=x0v.z; a_[3]=x0v.w;
      a_[4]=x1v.x; a_[5]=x1v.y; a_[6]=x1v.z; a_[7]=x1v.w;
    }
    #pragma unroll
    for (int pp = 0; pp < 8; ++pp) {
      float f_[8];
      f_[0] = rdlane(a_[0], pp); f_[1] = rdlane(a_[1], pp);
      f_[2] = rdlane(a_[2], pp); f_[3] = rdlane(a_[3], pp);
      f_[4] = rdlane(a_[4], pp); f_[5] = rdlane(a_[5], pp);
      f_[6] = rdlane(a_[6], pp); f_[7] = rdlane(a_[7], pp);
      // Quu >= I (pivot >= ~1): raw v_rcp (~2^-22 rel err) is plenty.
      float d = __builtin_amdgcn_rcpf(f_[pp]);
      a_[pp] *= d;
      #pragma unroll
      for (int r = 0; r < 8; ++r)
        if (r != pp) a_[r] = fmaf(-f_[r], a_[pp], a_[r]);
    }
    // gains: K = -X, k = -xq
    if (lane >= 8 && lane < 25) {
      float4 k0 = make_float4(-a_[0], -a_[1], -a_[2], -a_[3]);
      float4 k1 = make_float4(-a_[4], -a_[5], -a_[6], -a_[7]);
      float4* kp = (lane < 24) ? (float4*)&Ks[cid][tg][lane - 8][0]
                               : (float4*)&ksv[cid][tg][0];
      kp[0] = k0; kp[1] = k1;
    }
    // V-update spread over 64 lanes: lane (jv, ih) -> Vn[8ih..8ih+7][jv]
    const int jv = lane & 31;
    const int ih = lane >> 5;
    const int sl = (jv < 16) ? (8 + jv) : 24;
    float xj[8];
    #pragma unroll
    for (int c = 0; c < 8; ++c)
      xj[c] = __int_as_float(
          __builtin_amdgcn_ds_bpermute(sl * 4, __float_as_int(a_[c])));
    if (jv < 16 || jv == 24) {
      const int row2 = (jv < 16) ? jv : 24;
      const int s3 = (row2 >> 2) & 3;
      const float* b2p = &QhT[cid][0][0] + row2 * 36;
      const int q0 = 2 * ih, q1 = q0 + 1;
      float4 A0 = *(const float4*)(b2p + ((q0 ^ s3) << 2));
      float4 A1 = *(const float4*)(b2p + ((q1 ^ s3) << 2));
      float acc[8];
      acc[0]=A0.x; acc[1]=A0.y; acc[2]=A0.z; acc[3]=A0.w;
      acc[4]=A1.x; acc[5]=A1.y; acc[6]=A1.z; acc[7]=A1.w;
      #pragma unroll
      for (int c = 0; c < 8; ++c) {
        const int s2 = ((16 + c) >> 2) & 3;
        const float* qb = &QhT[cid][0][0] + (16 + c) * 36;
        float4 B0 = *(const float4*)(qb + ((q0 ^ s2) << 2));
        float4 B1 = *(const float4*)(qb + ((q1 ^ s2) << 2));
        const float xc = xj[c];
        acc[0] = fmaf(-xc, B0.x, acc[0]); acc[1] = fmaf(-xc, B0.y, acc[1]);
        acc[2] = fmaf(-xc, B0.z, acc[2]); acc[3] = fmaf(-xc, B0.w, acc[3]);
        acc[4] = fmaf(-xc, B1.x, acc[4]); acc[5] = fmaf(-xc, B1.y, acc[5]);
        acc[6] = fmaf(-xc, B1.z, acc[6]); acc[7] = fmaf(-xc, B1.w, acc[7]);
      }
      float4* vp = (jv < 16) ? (float4*)&VT[cid][jv][8 * ih]
                             : (float4*)&vv[cid][8 * ih];
      vp[0] = make_float4(acc[0], acc[1], acc[2], acc[3]);
      vp[1] = make_float4(acc[4], acc[5], acc[6], acc[7]);
    }
    __builtin_amdgcn_s_setprio(0);
  };

  // ---- prologue ----
  loadF(TT - 1);
  loadQ(TT - 1);
  if (cid == 0) { commitF(1); loadF(TT - 2); }  // P pre-commits F(127)
  bsync();

  // ===================== backward Riccati (antiphase) =====================
  for (int t = TT - 1; t >= 0; --t) {
    // interval 1: P.A(t) || Q.G(t+1) + Q-staging (commit F(t), load F(t-1))
    if (cid == 0) {
      phaseA(t);
    } else {
      if (t + 1 < TT) phaseG(t + 1);
      commitF(t & 1);
      if (t > 0) loadF(t - 1);
    }
    bsync();
    // interval 2: P.B(t) || Q.A(t)
    if (cid == 0) phaseB(t); else phaseA(t);
    bsync();
    // interval 3: P.G(t) + P-staging (commit F(t-1), load F(t-2)) || Q.B(t)
    if (cid == 0) {
      phaseG(t);
      if (t > 0) commitF((t - 1) & 1);
      if (t > 1) loadF(t - 2);
    } else {
      phaseB(t);
    }
    bsync();
  }
  // epilogue interval: Q finishes G(0)
  if (cid == 1) phaseG(0);
  bsync();

  // ===================== forward rollout (chain wave 0 only) ===============
  if (cwv != 0) return;

  float xv = (lane < 16) ? x0g[(size_t)b2 * 16 + lane] : 0.f;
  float xs_[16];
  #pragma unroll
  for (int i = 0; i < 16; ++i) xs_[i] = rdlane(xv, i);

  float FA[24], FB[24];
  float cA = 0.f, cB = 0.f;
  float KA[16], KB[16], kA = 0.f, kB = 0.f;

  auto loadFw = [&](int t, float (&Fr)[24], float& cr) {
    if (lane < 16) {
      const float* src = Fg + (bt0 + t) * 384 + lane * 24;
      #pragma unroll
      for (int r = 0; r < 6; ++r) {
        float4 f4v = ((const float4*)src)[r];
        Fr[4*r+0] = f4v.x; Fr[4*r+1] = f4v.y; Fr[4*r+2] = f4v.z; Fr[4*r+3] = f4v.w;
      }
      cr = cg[(bt0 + t) * 16 + lane];
    }
  };
  auto loadK = [&](int t, float (&K)[16], float& kk) {
    if (lane < 8) {
      #pragma unroll
      for (int i = 0; i < 16; ++i) K[i] = Ks[cid][t][i][lane];
      kk = ksv[cid][t][lane];
    }
  };

  auto fstep = [&](int t, const float (&Fr)[24], float cr,
                   const float (&K)[16], float kk) {
    float uv = 0.f;
    if (lane < 8) {
      float u0 = kk, u1 = 0.f;
      #pragma unroll
      for (int i = 0; i < 16; i += 2) {
        u0 = fmaf(K[i],     xs_[i],     u0);
        u1 = fmaf(K[i + 1], xs_[i + 1], u1);
      }
      uv = u0 + u1;
    }
    float us[8];
    #pragma unroll
    for (int c = 0; c < 8; ++c) us[c] = rdlane(uv, c);
    float* o = out + (bt0 + t) * 24;
    if (lane < 16) o[lane] = xv;
    if (lane < 8)  o[16 + lane] = uv;
    float x0a = cr, x1a = 0.f;
    #pragma unroll
    for (int j2 = 0; j2 < 16; j2 += 2) {
      x0a = fmaf(Fr[j2],     xs_[j2],     x0a);
      x1a = fmaf(Fr[j2 + 1], xs_[j2 + 1], x1a);
    }
    #pragma unroll
    for (int c = 0; c < 8; c += 2) {
      x0a = fmaf(Fr[16 + c],     us[c],     x0a);
      x1a = fmaf(Fr[16 + c + 1], us[c + 1], x1a);
    }
    xv = x0a + x1a;
    #pragma unroll
    for (int i = 0; i < 16; ++i) xs_[i] = rdlane(xv, i);
  };

  loadFw(0, FA, cA); loadK(0, KA, kA);
  for (int t = 0; t < TT; t += 2) {
    if (t + 1 < TT) { loadFw(t + 1, FB, cB); loadK(t + 1, KB, kB); }
    fstep(t, FA, cA, KA, kA);
    if (t + 2 < TT) { loadFw(t + 2, FA, cA); loadK(t + 2, KA, kA); }
    fstep(t + 1, FB, cB, KB, kB);
  }
}
} // namespace

extern "C" void kernel_launch(void* const* d_in, const int* in_sizes, int n_in,
                              void* d_out, int out_size, void* d_ws, size_t ws_size,
                              hipStream_t stream)
{
  (void)n_in; (void)out_size; (void)d_ws; (void)ws_size;
  const float* Q  = (const float*)d_in[0];
  const float* p  = (const float*)d_in[1];
  const float* F  = (const float*)d_in[2];
  const float* c1 = (const float*)d_in[3];
  const float* x0 = (const float*)d_in[4];
  float* outp = (float*)d_out;

  const int B = in_sizes[4] / 16;   // 512 chains
  lqr_kernel<<<B / 2, 512, 0, stream>>>(Q, p, F, c1, x0, outp);
}

// Round 10
// 313.643 us; speedup vs baseline: 1.1348x; 1.1348x over previous
//
#include <hip/hip_runtime.h>

namespace {
constexpr int TT = 128;

__device__ __forceinline__ float rdlane(float v, int l) {
  return __int_as_float(__builtin_amdgcn_readlane(__float_as_int(v), l));
}

__device__ __forceinline__ void bsync() {
  // 512-thread barrier WITHOUT vmcnt drain: global prefetches stay in flight.
  asm volatile("s_waitcnt lgkmcnt(0)" ::: "memory");
  __builtin_amdgcn_s_barrier();
  asm volatile("" ::: "memory");
  __builtin_amdgcn_sched_barrier(0);
}

// Two chains per block (P = waves 0-3, Q = waves 4-7), SYMMETRIC lockstep:
// both chains run the same phase in each barrier interval (interval = max over
// identical phases = phase length). GJ waves are SIMD-disjoint across chains.
__global__ __launch_bounds__(512)
void lqr_kernel(const float* __restrict__ Qg, const float* __restrict__ pg,
                const float* __restrict__ Fg, const float* __restrict__ cg,
                const float* __restrict__ x0g, float* __restrict__ out)
{
  // Quad-XOR-swizzled tiles: element (row, n) at row*S + ((n>>2 ^ ((row>>2)&3))<<2) + (n&3)
  __shared__ __align__(16) float VT[2][16][20];
  __shared__ __align__(16) float vv[2][16];
  __shared__ __align__(16) float FTxd[2][2][25][20]; // [chain][dbuf]
  __shared__ __align__(16) float WTx[2][25][20];
  __shared__ __align__(16) float QhT[2][25][36];
  __shared__ __align__(16) float Ks[2][TT][16][8];   // Ks[c][t][j][cc] = K[cc][j]
  __shared__ __align__(16) float ksv[2][TT][8];

  const int tid  = threadIdx.x;
  const int cid  = tid >> 8;        // chain: 0 = P, 1 = Q
  const int ctid = tid & 255;       // chain-local tid
  const int lane = ctid & 63;
  const int cwv  = ctid >> 6;       // chain-local wave 0..3
  const int b2   = blockIdx.x * 2 + cid;
  const size_t bt0 = (size_t)b2 * TT;

  const int jl = ctid & 31;         // per-lane column index (valid <25 / <24)
  const int g  = ctid >> 5;         // 0..7, uniform per half-wave

  // zero V (320 floats) + v per chain
  for (int e = ctid; e < 320; e += 256) (&VT[cid][0][0])[e] = 0.f;
  if (ctid < 16) vv[cid][ctid] = 0.f;

  // ---- F/c staging: unit u = ctid < 100 (chain-local waves 0-1 only)
  const int  fj   = ctid >> 2, fk = ctid & 3;
  const bool fact = (ctid < 100);
  const int  fsw  = (fj < 24) ? ((fj >> 2) & 3) : 2;
  float Fr4[4] = {0.f, 0.f, 0.f, 0.f};
  float qreg[3] = {0.f, 0.f, 0.f}, qreg3 = 0.f;
  float fr[16];                     // F column cache, set in A, used in B

  auto loadF = [&](int t) {
    if (fact) {
      if (fj < 24) {
        const float* Fs = Fg + (bt0 + t) * 384 + fj;
        #pragma unroll
        for (int m = 0; m < 4; ++m) Fr4[m] = Fs[(4 * fk + m) * 24];
      } else {
        const float* cs = cg + (bt0 + t) * 16 + 4 * fk;
        #pragma unroll
        for (int m = 0; m < 4; ++m) Fr4[m] = cs[m];
      }
    }
  };
  auto commitF = [&](int buf) {
    if (fact) {
      float* dst = &FTxd[cid][buf][fj][(fk ^ fsw) << 2];
      *(float4*)dst = make_float4(Fr4[0], Fr4[1], Fr4[2], Fr4[3]);
    }
  };
  auto loadQ = [&](int t) {
    if (jl < 24) {
      const float* Qs = Qg + (bt0 + t) * 576;
      #pragma unroll
      for (int r = 0; r < 3; ++r) qreg[r] = Qs[(3 * g + r) * 24 + jl]; // Q sym
      if (g == 7) qreg3 = pg[(bt0 + t) * 24 + jl];
    }
  };

  // Phase A: WTx[j][m] = sum_n V[m][n] * F[n][j]  (+v for j==24 -> z)
  auto phaseA = [&](int t) {
    const float* Fb = &FTxd[cid][t & 1][0][0];
    if (jl < 25) {
      const int sj = (jl >> 2) & 3;
      const float* fb = Fb + jl * 20;
      #pragma unroll
      for (int q = 0; q < 4; ++q) {
        float4 v4 = *(const float4*)(fb + ((q ^ sj) << 2));
        fr[4*q+0] = v4.x; fr[4*q+1] = v4.y; fr[4*q+2] = v4.z; fr[4*q+3] = v4.w;
      }
      const int m0 = 2 * g, m1 = m0 + 1;
      float acc0 = (jl == 24) ? vv[cid][m0] : 0.f;
      float acc1 = (jl == 24) ? vv[cid][m1] : 0.f;
      #pragma unroll
      for (int q = 0; q < 4; ++q) {
        float4 a0 = *(const float4*)(&VT[cid][m0][4*q]);  // broadcast/half-wave
        float4 a1 = *(const float4*)(&VT[cid][m1][4*q]);
        acc0 = fmaf(a0.x, fr[4*q+0], acc0); acc0 = fmaf(a0.y, fr[4*q+1], acc0);
        acc0 = fmaf(a0.z, fr[4*q+2], acc0); acc0 = fmaf(a0.w, fr[4*q+3], acc0);
        acc1 = fmaf(a1.x, fr[4*q+0], acc1); acc1 = fmaf(a1.y, fr[4*q+1], acc1);
        acc1 = fmaf(a1.z, fr[4*q+2], acc1); acc1 = fmaf(a1.w, fr[4*q+3], acc1);
      }
      float* wb = &WTx[cid][0][0] + jl * 20;
      *(float2*)(wb + ((((g >> 1) ^ sj) << 2) + (m0 & 3))) = make_float2(acc0, acc1);
    }
  };

  // Phase B: QhT[c][i] = Qsrc + sum_m F[m][i] * W[m][c]   (i = jl)
  auto phaseB = [&](int t) {
    if (jl < 24) {
      #pragma unroll
      for (int r = 0; r < 3; ++r) {
        const int c = 3 * g + r;
        const int sc = (c >> 2) & 3;
        const float* wb = &WTx[cid][0][0] + c * 20;   // broadcast per half-wave
        float acc = qreg[r];
        #pragma unroll
        for (int q = 0; q < 4; ++q) {
          float4 w4 = *(const float4*)(wb + ((q ^ sc) << 2));
          acc = fmaf(w4.x, fr[4*q+0], acc); acc = fmaf(w4.y, fr[4*q+1], acc);
          acc = fmaf(w4.z, fr[4*q+2], acc); acc = fmaf(w4.w, fr[4*q+3], acc);
        }
        float* qb = &QhT[cid][0][0] + c * 36;
        qb[(((jl >> 2) ^ sc) << 2) + (jl & 3)] = acc;
      }
      if (g == 7) {                               // qh row (c==24), s=2
        const float* wb = &WTx[cid][0][0] + 24 * 20;
        float acc = qreg3;
        #pragma unroll
        for (int q = 0; q < 4; ++q) {
          float4 w4 = *(const float4*)(wb + ((q ^ 2) << 2));
          acc = fmaf(w4.x, fr[4*q+0], acc); acc = fmaf(w4.y, fr[4*q+1], acc);
          acc = fmaf(w4.z, fr[4*q+2], acc); acc = fmaf(w4.w, fr[4*q+3], acc);
        }
        float* qb = &QhT[cid][0][0] + 24 * 36;
        qb[(((jl >> 2) ^ 2) << 2) + (jl & 3)] = acc;
      }
    }
    if (t > 0) loadQ(t - 1);
  };

  // GJ + gains + V-update on wave gw (caller guarantees gw in {2,3}: disjoint
  // from staging waves 0-1 for BOTH chains).
  auto phaseG = [&](int tg, int gw) {
    if (cwv != gw) return;
    __builtin_amdgcn_s_setprio(1);
    // lanes 0..7 = Quu cols, 8..23 = Qux cols (x-col j at lane 8+j), 24 = qu
    const int cl = (lane < 25) ? lane : 0;
    const int row = (cl < 8) ? (16 + cl) : ((cl < 24) ? (cl - 8) : 24);
    const int s = (row >> 2) & 3;
    const float* base = &QhT[cid][0][0] + row * 36;
    float a_[8];
    {
      float4 x0v = *(const float4*)(base + ((4 ^ s) << 2));
      float4 x1v = *(const float4*)(base + ((5 ^ s) << 2));
      a_[0]=x0v.x; a_[1]=x0v.y; a_[2]=x0v.z; a_[3]=x0v.w;
      a_[4]=x1v.x; a_[5]=x1v.y; a_[6]=x1v.z; a_[7]=x1v.w;
    }
    #pragma unroll
    for (int pp = 0; pp < 8; ++pp) {
      float f_[8];
      f_[0] = rdlane(a_[0], pp); f_[1] = rdlane(a_[1], pp);
      f_[2] = rdlane(a_[2], pp); f_[3] = rdlane(a_[3], pp);
      f_[4] = rdlane(a_[4], pp); f_[5] = rdlane(a_[5], pp);
      f_[6] = rdlane(a_[6], pp); f_[7] = rdlane(a_[7], pp);
      // Quu >= I (pivot >= ~1): raw v_rcp (~2^-22 rel err) is plenty.
      float d = __builtin_amdgcn_rcpf(f_[pp]);
      a_[pp] *= d;
      #pragma unroll
      for (int r = 0; r < 8; ++r)
        if (r != pp) a_[r] = fmaf(-f_[r], a_[pp], a_[r]);
    }
    // gains: K = -X, k = -xq
    if (lane >= 8 && lane < 25) {
      float4 k0 = make_float4(-a_[0], -a_[1], -a_[2], -a_[3]);
      float4 k1 = make_float4(-a_[4], -a_[5], -a_[6], -a_[7]);
      float4* kp = (lane < 24) ? (float4*)&Ks[cid][tg][lane - 8][0]
                               : (float4*)&ksv[cid][tg][0];
      kp[0] = k0; kp[1] = k1;
    }
    // V-update spread over 64 lanes: lane (jv, ih) -> Vn[8ih..8ih+7][jv]
    const int jv = lane & 31;
    const int ih = lane >> 5;
    const int sl = (jv < 16) ? (8 + jv) : 24;
    float xj[8];
    #pragma unroll
    for (int c = 0; c < 8; ++c)
      xj[c] = __int_as_float(
          __builtin_amdgcn_ds_bpermute(sl * 4, __float_as_int(a_[c])));
    if (jv < 16 || jv == 24) {
      const int row2 = (jv < 16) ? jv : 24;
      const int s3 = (row2 >> 2) & 3;
      const float* b2p = &QhT[cid][0][0] + row2 * 36;
      const int q0 = 2 * ih, q1 = q0 + 1;
      float4 A0 = *(const float4*)(b2p + ((q0 ^ s3) << 2));
      float4 A1 = *(const float4*)(b2p + ((q1 ^ s3) << 2));
      float acc[8];
      acc[0]=A0.x; acc[1]=A0.y; acc[2]=A0.z; acc[3]=A0.w;
      acc[4]=A1.x; acc[5]=A1.y; acc[6]=A1.z; acc[7]=A1.w;
      #pragma unroll
      for (int c = 0; c < 8; ++c) {
        const int s2 = ((16 + c) >> 2) & 3;
        const float* qb = &QhT[cid][0][0] + (16 + c) * 36;
        float4 B0 = *(const float4*)(qb + ((q0 ^ s2) << 2));
        float4 B1 = *(const float4*)(qb + ((q1 ^ s2) << 2));
        const float xc = xj[c];
        acc[0] = fmaf(-xc, B0.x, acc[0]); acc[1] = fmaf(-xc, B0.y, acc[1]);
        acc[2] = fmaf(-xc, B0.z, acc[2]); acc[3] = fmaf(-xc, B0.w, acc[3]);
        acc[4] = fmaf(-xc, B1.x, acc[4]); acc[5] = fmaf(-xc, B1.y, acc[5]);
        acc[6] = fmaf(-xc, B1.z, acc[6]); acc[7] = fmaf(-xc, B1.w, acc[7]);
      }
      float4* vp = (jv < 16) ? (float4*)&VT[cid][jv][8 * ih]
                             : (float4*)&vv[cid][8 * ih];
      vp[0] = make_float4(acc[0], acc[1], acc[2], acc[3]);
      vp[1] = make_float4(acc[4], acc[5], acc[6], acc[7]);
    }
    __builtin_amdgcn_s_setprio(0);
  };

  // ---- prologue (both chains) ----
  loadF(TT - 1);
  loadQ(TT - 1);
  commitF(1);
  loadF(TT - 2);
  bsync();

  // ===================== backward Riccati (symmetric lockstep) =============
  for (int t = TT - 1; t >= 0; --t) {
    // I1: both chains Phase A
    phaseA(t);
    bsync();
    // I2: both chains Phase B (+ Q prefetch)
    phaseB(t);
    bsync();
    // I3: GJ (chain P on wave 2+(t&1) -> SIMD 2/3; chain Q on wave 3-(t&1)
    //     -> the other SIMD) || staging on chain-local waves 0-1
    {
      const int gw = (cid == 0) ? (2 + (t & 1)) : (3 - (t & 1));
      if (cwv == gw) {
        phaseG(t, gw);
      } else {
        if (t > 0) commitF((t - 1) & 1);
        if (t > 1) loadF(t - 2);
      }
    }
    bsync();
  }

  // ===================== forward rollout (chain-local wave 0) ==============
  if (cwv != 0) return;

  float xv = (lane < 16) ? x0g[(size_t)b2 * 16 + lane] : 0.f;
  float xs_[16];
  #pragma unroll
  for (int i = 0; i < 16; ++i) xs_[i] = rdlane(xv, i);

  float FA[24], FB[24];
  float cA = 0.f, cB = 0.f;
  float KA[16], KB[16], kA = 0.f, kB = 0.f;

  auto loadFw = [&](int t, float (&Fr)[24], float& cr) {
    if (lane < 16) {
      const float* src = Fg + (bt0 + t) * 384 + lane * 24;
      #pragma unroll
      for (int r = 0; r < 6; ++r) {
        float4 f4v = ((const float4*)src)[r];
        Fr[4*r+0] = f4v.x; Fr[4*r+1] = f4v.y; Fr[4*r+2] = f4v.z; Fr[4*r+3] = f4v.w;
      }
      cr = cg[(bt0 + t) * 16 + lane];
    }
  };
  auto loadK = [&](int t, float (&K)[16], float& kk) {
    if (lane < 8) {
      #pragma unroll
      for (int i = 0; i < 16; ++i) K[i] = Ks[cid][t][i][lane];
      kk = ksv[cid][t][lane];
    }
  };

  auto fstep = [&](int t, const float (&Fr)[24], float cr,
                   const float (&K)[16], float kk) {
    float uv = 0.f;
    if (lane < 8) {
      float u0 = kk, u1 = 0.f;
      #pragma unroll
      for (int i = 0; i < 16; i += 2) {
        u0 = fmaf(K[i],     xs_[i],     u0);
        u1 = fmaf(K[i + 1], xs_[i + 1], u1);
      }
      uv = u0 + u1;
    }
    float us[8];
    #pragma unroll
    for (int c = 0; c < 8; ++c) us[c] = rdlane(uv, c);
    float* o = out + (bt0 + t) * 24;
    if (lane < 16) o[lane] = xv;
    if (lane < 8)  o[16 + lane] = uv;
    float x0a = cr, x1a = 0.f;
    #pragma unroll
    for (int j2 = 0; j2 < 16; j2 += 2) {
      x0a = fmaf(Fr[j2],     xs_[j2],     x0a);
      x1a = fmaf(Fr[j2 + 1], xs_[j2 + 1], x1a);
    }
    #pragma unroll
    for (int c = 0; c < 8; c += 2) {
      x0a = fmaf(Fr[16 + c],     us[c],     x0a);
      x1a = fmaf(Fr[16 + c + 1], us[c + 1], x1a);
    }
    xv = x0a + x1a;
    #pragma unroll
    for (int i = 0; i < 16; ++i) xs_[i] = rdlane(xv, i);
  };

  loadFw(0, FA, cA); loadK(0, KA, kA);
  for (int t = 0; t < TT; t += 2) {
    if (t + 1 < TT) { loadFw(t + 1, FB, cB); loadK(t + 1, KB, kB); }
    fstep(t, FA, cA, KA, kA);
    if (t + 2 < TT) { loadFw(t + 2, FA, cA); loadK(t + 2, KA, kA); }
    fstep(t + 1, FB, cB, KB, kB);
  }
}
} // namespace

extern "C" void kernel_launch(void* const* d_in, const int* in_sizes, int n_in,
                              void* d_out, int out_size, void* d_ws, size_t ws_size,
                              hipStream_t stream)
{
  (void)n_in; (void)out_size; (void)d_ws; (void)ws_size;
  const float* Q  = (const float*)d_in[0];
  const float* p  = (const float*)d_in[1];
  const float* F  = (const float*)d_in[2];
  const float* c1 = (const float*)d_in[3];
  const float* x0 = (const float*)d_in[4];
  float* outp = (float*)d_out;

  const int B = in_sizes[4] / 16;   // 512 chains
  lqr_kernel<<<B / 2, 512, 0, stream>>>(Q, p, F, c1, x0, outp);
}

// Round 12
// 294.150 us; speedup vs baseline: 1.2100x; 1.0663x over previous
//
#include <hip/hip_runtime.h>

namespace {
constexpr int TT = 128;

__device__ __forceinline__ float rdlane(float v, int l) {
  return __int_as_float(__builtin_amdgcn_readlane(__float_as_int(v), l));
}

__device__ __forceinline__ void bsync() {
  // 256-thread barrier WITHOUT vmcnt drain: global prefetches stay in flight.
  asm volatile("s_waitcnt lgkmcnt(0)" ::: "memory");
  __builtin_amdgcn_s_barrier();
  asm volatile("" ::: "memory");
  __builtin_amdgcn_sched_barrier(0);
}

__global__ __launch_bounds__(256)
void lqr_kernel(const float* __restrict__ Qg, const float* __restrict__ pg,
                const float* __restrict__ Fg, const float* __restrict__ cg,
                const float* __restrict__ x0g, float* __restrict__ out)
{
  // Quad-XOR-swizzled tiles: element (row, n) at row*S + ((n>>2 ^ ((row>>2)&3))<<2) + (n&3)
  __shared__ __align__(16) float VT[16][20];     // plain; V columns (symmetric)
  __shared__ __align__(16) float vv[16];
  __shared__ __align__(16) float FTxd[2][25][20];// swz; rows 0..23 = F cols, 24 = c
  __shared__ __align__(16) float WTx[25][20];    // swz; rows = W^T cols, 24 = z
  __shared__ __align__(16) float QhT[25][36];    // swz; rows = Qh cols, 24 = qh
  __shared__ __align__(16) float Ks[TT][16][8];  // Ks[t][j][c] = K[c][j]
  __shared__ __align__(16) float ksv[TT][8];

  const int tid  = threadIdx.x;
  const int lane = tid & 63;
  const int wv   = tid >> 6;
  const int b    = blockIdx.x;
  const size_t bt0 = (size_t)b * TT;

  const int jl = tid & 31;   // per-lane column index (valid <25 / <24)
  const int g  = tid >> 5;   // 0..7, uniform per half-wave

  // zero ALL of VT (320 floats) + vv
  for (int e = tid; e < 320; e += 256) (&VT[0][0])[e] = 0.f;
  if (tid < 16) vv[tid] = 0.f;

  // ---- F/c staging: unit u = tid < 100 (waves 0-1 only): j = u>>2, k = u&3
  const int  fj   = tid >> 2, fk = tid & 3;
  const bool fact = (tid < 100);
  const int  fsw  = (fj < 24) ? ((fj >> 2) & 3) : 2;
  float Fr4[4] = {0.f, 0.f, 0.f, 0.f};

  auto loadF = [&](int t) {
    if (fact) {
      if (fj < 24) {
        const float* Fs = Fg + (bt0 + t) * 384 + fj;
        #pragma unroll
        for (int m = 0; m < 4; ++m) Fr4[m] = Fs[(4 * fk + m) * 24];
      } else {
        const float* cs = cg + (bt0 + t) * 16 + 4 * fk;
        #pragma unroll
        for (int m = 0; m < 4; ++m) Fr4[m] = cs[m];
      }
    }
  };
  auto commitF = [&](int buf) {
    if (fact) {
      float* dst = &FTxd[buf][fj][(fk ^ fsw) << 2];
      *(float4*)dst = make_float4(Fr4[0], Fr4[1], Fr4[2], Fr4[3]);
    }
  };

  float qreg[3] = {0.f, 0.f, 0.f}, qreg3 = 0.f;
  auto loadQ = [&](int t) {
    if (jl < 24) {
      const float* Qs = Qg + (bt0 + t) * 576;
      #pragma unroll
      for (int r = 0; r < 3; ++r) qreg[r] = Qs[(3 * g + r) * 24 + jl]; // Q sym
      if (g == 7) qreg3 = pg[(bt0 + t) * 24 + jl];
    }
  };

  // ---- prologue ----
  loadF(TT - 1);
  loadQ(TT - 1);
  commitF(1);
  loadF(TT - 2);
  bsync();

  // ===================== backward Riccati =====================
  for (int t = TT - 1; t >= 0; --t) {
    const float* Fb = &FTxd[t & 1][0][0];

    // Phase A: WTx[j][m] = sum_n V[m][n] * F[n][j]  (+v for j==24 -> z)
    float fr[16];
    if (jl < 25) {
      const int sj = (jl >> 2) & 3;
      const float* fb = Fb + jl * 20;
      #pragma unroll
      for (int q = 0; q < 4; ++q) {
        float4 v4 = *(const float4*)(fb + ((q ^ sj) << 2));
        fr[4*q+0] = v4.x; fr[4*q+1] = v4.y; fr[4*q+2] = v4.z; fr[4*q+3] = v4.w;
      }
      const int m0 = 2 * g, m1 = m0 + 1;
      float acc0 = (jl == 24) ? vv[m0] : 0.f;
      float acc1 = (jl == 24) ? vv[m1] : 0.f;
      #pragma unroll
      for (int q = 0; q < 4; ++q) {
        float4 a0 = *(const float4*)(&VT[m0][4*q]);   // broadcast per half-wave
        float4 a1 = *(const float4*)(&VT[m1][4*q]);
        acc0 = fmaf(a0.x, fr[4*q+0], acc0); acc0 = fmaf(a0.y, fr[4*q+1], acc0);
        acc0 = fmaf(a0.z, fr[4*q+2], acc0); acc0 = fmaf(a0.w, fr[4*q+3], acc0);
        acc1 = fmaf(a1.x, fr[4*q+0], acc1); acc1 = fmaf(a1.y, fr[4*q+1], acc1);
        acc1 = fmaf(a1.z, fr[4*q+2], acc1); acc1 = fmaf(a1.w, fr[4*q+3], acc1);
      }
      float* wb = &WTx[0][0] + jl * 20;
      *(float2*)(wb + ((((g >> 1) ^ sj) << 2) + (m0 & 3))) = make_float2(acc0, acc1);
    }
    bsync();

    // Phase B: QhT[c][i] = Qsrc + sum_m F[m][i] * W[m][c]   (i = jl)
    if (jl < 24) {
      #pragma unroll
      for (int r = 0; r < 3; ++r) {
        const int c = 3 * g + r;
        const int sc = (c >> 2) & 3;
        const float* wb = &WTx[0][0] + c * 20;   // broadcast per half-wave
        float acc = qreg[r];
        #pragma unroll
        for (int q = 0; q < 4; ++q) {
          float4 w4 = *(const float4*)(wb + ((q ^ sc) << 2));
          acc = fmaf(w4.x, fr[4*q+0], acc); acc = fmaf(w4.y, fr[4*q+1], acc);
          acc = fmaf(w4.z, fr[4*q+2], acc); acc = fmaf(w4.w, fr[4*q+3], acc);
        }
        float* qb = &QhT[0][0] + c * 36;
        qb[(((jl >> 2) ^ sc) << 2) + (jl & 3)] = acc;
      }
      if (g == 7) {                               // qh row (c==24), s=2
        const float* wb = &WTx[0][0] + 24 * 20;
        float acc = qreg3;
        #pragma unroll
        for (int q = 0; q < 4; ++q) {
          float4 w4 = *(const float4*)(wb + ((q ^ 2) << 2));
          acc = fmaf(w4.x, fr[4*q+0], acc); acc = fmaf(w4.y, fr[4*q+1], acc);
          acc = fmaf(w4.z, fr[4*q+2], acc); acc = fmaf(w4.w, fr[4*q+3], acc);
        }
        float* qb = &QhT[0][0] + 24 * 36;
        qb[(((jl >> 2) ^ 2) << 2) + (jl & 3)] = acc;
      }
    }
    if (t > 0) loadQ(t - 1);
    bsync();

    // ---- G': redundant elimination on ALL waves + 4-way-split V-update ----
    {
      // staging first: issue F(t-2) global loads early; commit F(t-1) tile
      // (waves 0-1 via fact; no wave reads FTxd[(t-1)&1] until next interval)
      if (t > 0) commitF((t - 1) & 1);
      if (t > 1) loadF(t - 2);

      // elimination inputs: lanes 0..7 = Quu cols, 8..23 = Qux cols (x-col j
      // at lane 8+j), 24 = qu. Identical on every wave -> bitwise-same a_.
      const int cl = (lane < 25) ? lane : 0;
      const int row = (cl < 8) ? (16 + cl) : ((cl < 24) ? (cl - 8) : 24);
      const int s = (row >> 2) & 3;
      const float* base = &QhT[0][0] + row * 36;
      float a_[8];
      {
        float4 x0v = *(const float4*)(base + ((4 ^ s) << 2));
        float4 x1v = *(const float4*)(base + ((5 ^ s) << 2));
        a_[0]=x0v.x; a_[1]=x0v.y; a_[2]=x0v.z; a_[3]=x0v.w;
        a_[4]=x1v.x; a_[5]=x1v.y; a_[6]=x1v.z; a_[7]=x1v.w;
      }

      // pre-issue V-update reads: latency hides under the elimination chain.
      // wave wv owns Vn rows 4wv..4wv+3; lane jv owns column jv (jv<16 or 24).
      const int jv = (lane < 25) ? lane : 0;
      const bool vact = (lane < 25) && ((jv < 16) || (jv == 24));
      const int row2 = (jv < 16) ? jv : 24;
      const int s3 = (row2 >> 2) & 3;
      float4 A0 = *(const float4*)(&QhT[0][0] + row2 * 36 + ((wv ^ s3) << 2));
      float4 Bv0, Bv1, Bv2, Bv3, Bv4, Bv5, Bv6, Bv7;
      {
        const float* q16 = &QhT[0][0];
        Bv0 = *(const float4*)(q16 + 16 * 36 + ((wv ^ 0) << 2));
        Bv1 = *(const float4*)(q16 + 17 * 36 + ((wv ^ 0) << 2));
        Bv2 = *(const float4*)(q16 + 18 * 36 + ((wv ^ 0) << 2));
        Bv3 = *(const float4*)(q16 + 19 * 36 + ((wv ^ 0) << 2));
        Bv4 = *(const float4*)(q16 + 20 * 36 + ((wv ^ 1) << 2));
        Bv5 = *(const float4*)(q16 + 21 * 36 + ((wv ^ 1) << 2));
        Bv6 = *(const float4*)(q16 + 22 * 36 + ((wv ^ 1) << 2));
        Bv7 = *(const float4*)(q16 + 23 * 36 + ((wv ^ 1) << 2));
      }

      // ---- 8-pivot elimination (R8 verbatim) ----
      #pragma unroll
      for (int pp = 0; pp < 8; ++pp) {
        float f_[8];
        f_[0] = rdlane(a_[0], pp); f_[1] = rdlane(a_[1], pp);
        f_[2] = rdlane(a_[2], pp); f_[3] = rdlane(a_[3], pp);
        f_[4] = rdlane(a_[4], pp); f_[5] = rdlane(a_[5], pp);
        f_[6] = rdlane(a_[6], pp); f_[7] = rdlane(a_[7], pp);
        // Quu >= I (pivot >= ~1): raw v_rcp (~2^-22 rel err) is plenty.
        float d = __builtin_amdgcn_rcpf(f_[pp]);
        a_[pp] *= d;
        #pragma unroll
        for (int r = 0; r < 8; ++r)
          if (r != pp) a_[r] = fmaf(-f_[r], a_[pp], a_[r]);
      }

      // K-write from wave 3 only (staging-disjoint): K = -X, k = -xq
      if (wv == 3 && lane >= 8 && lane < 25) {
        float4 k0 = make_float4(-a_[0], -a_[1], -a_[2], -a_[3]);
        float4 k1 = make_float4(-a_[4], -a_[5], -a_[6], -a_[7]);
        float4* kp = (lane < 24) ? (float4*)&Ks[t][lane - 8][0]
                                 : (float4*)&ksv[t][0];
        kp[0] = k0; kp[1] = k1;
      }

      // V-update quarter wv: Vn[4wv+r][jv] = Qxx[..][jv] - sum_c Qxu[..][c]*X[c][jv]
      const int sl = (jv < 16) ? (8 + jv) : 24;
      float xj[8];
      #pragma unroll
      for (int c = 0; c < 8; ++c)
        xj[c] = __int_as_float(
            __builtin_amdgcn_ds_bpermute(sl * 4, __float_as_int(a_[c])));
      if (vact) {
        float acc[4];
        acc[0] = A0.x; acc[1] = A0.y; acc[2] = A0.z; acc[3] = A0.w;
        acc[0] = fmaf(-xj[0], Bv0.x, acc[0]); acc[1] = fmaf(-xj[0], Bv0.y, acc[1]);
        acc[2] = fmaf(-xj[0], Bv0.z, acc[2]); acc[3] = fmaf(-xj[0], Bv0.w, acc[3]);
        acc[0] = fmaf(-xj[1], Bv1.x, acc[0]); acc[1] = fmaf(-xj[1], Bv1.y, acc[1]);
        acc[2] = fmaf(-xj[1], Bv1.z, acc[2]); acc[3] = fmaf(-xj[1], Bv1.w, acc[3]);
        acc[0] = fmaf(-xj[2], Bv2.x, acc[0]); acc[1] = fmaf(-xj[2], Bv2.y, acc[1]);
        acc[2] = fmaf(-xj[2], Bv2.z, acc[2]); acc[3] = fmaf(-xj[2], Bv2.w, acc[3]);
        acc[0] = fmaf(-xj[3], Bv3.x, acc[0]); acc[1] = fmaf(-xj[3], Bv3.y, acc[1]);
        acc[2] = fmaf(-xj[3], Bv3.z, acc[2]); acc[3] = fmaf(-xj[3], Bv3.w, acc[3]);
        acc[0] = fmaf(-xj[4], Bv4.x, acc[0]); acc[1] = fmaf(-xj[4], Bv4.y, acc[1]);
        acc[2] = fmaf(-xj[4], Bv4.z, acc[2]); acc[3] = fmaf(-xj[4], Bv4.w, acc[3]);
        acc[0] = fmaf(-xj[5], Bv5.x, acc[0]); acc[1] = fmaf(-xj[5], Bv5.y, acc[1]);
        acc[2] = fmaf(-xj[5], Bv5.z, acc[2]); acc[3] = fmaf(-xj[5], Bv5.w, acc[3]);
        acc[0] = fmaf(-xj[6], Bv6.x, acc[0]); acc[1] = fmaf(-xj[6], Bv6.y, acc[1]);
        acc[2] = fmaf(-xj[6], Bv6.z, acc[2]); acc[3] = fmaf(-xj[6], Bv6.w, acc[3]);
        acc[0] = fmaf(-xj[7], Bv7.x, acc[0]); acc[1] = fmaf(-xj[7], Bv7.y, acc[1]);
        acc[2] = fmaf(-xj[7], Bv7.z, acc[2]); acc[3] = fmaf(-xj[7], Bv7.w, acc[3]);
        float* vp = (jv < 16) ? &VT[jv][4 * wv] : &vv[4 * wv];
        *(float4*)vp = make_float4(acc[0], acc[1], acc[2], acc[3]);
      }
    }
    bsync();
  }

  // ===================== forward rollout (wave 0 only) =====================
  if (wv != 0) return;

  float xv = (lane < 16) ? x0g[(size_t)b * 16 + lane] : 0.f;
  float xs_[16];
  #pragma unroll
  for (int i = 0; i < 16; ++i) xs_[i] = rdlane(xv, i);

  float FA[24], FB[24];
  float cA = 0.f, cB = 0.f;
  float KA[16], KB[16], kA = 0.f, kB = 0.f;

  auto loadFw = [&](int t, float (&Fr)[24], float& cr) {
    if (lane < 16) {
      const float* src = Fg + (bt0 + t) * 384 + lane * 24;
      #pragma unroll
      for (int r = 0; r < 6; ++r) {
        float4 f4v = ((const float4*)src)[r];
        Fr[4*r+0] = f4v.x; Fr[4*r+1] = f4v.y; Fr[4*r+2] = f4v.z; Fr[4*r+3] = f4v.w;
      }
      cr = cg[(bt0 + t) * 16 + lane];
    }
  };
  auto loadK = [&](int t, float (&K)[16], float& kk) {
    if (lane < 8) {
      #pragma unroll
      for (int i = 0; i < 16; ++i) K[i] = Ks[t][i][lane];
      kk = ksv[t][lane];
    }
  };

  auto fstep = [&](int t, const float (&Fr)[24], float cr,
                   const float (&K)[16], float kk) {
    float uv = 0.f;
    if (lane < 8) {
      float u0 = kk, u1 = 0.f;
      #pragma unroll
      for (int i = 0; i < 16; i += 2) {
        u0 = fmaf(K[i],     xs_[i],     u0);
        u1 = fmaf(K[i + 1], xs_[i + 1], u1);
      }
      uv = u0 + u1;
    }
    float us[8];
    #pragma unroll
    for (int c = 0; c < 8; ++c) us[c] = rdlane(uv, c);
    float* o = out + (bt0 + t) * 24;
    if (lane < 16) o[lane] = xv;
    if (lane < 8)  o[16 + lane] = uv;
    float x0a = cr, x1a = 0.f;
    #pragma unroll
    for (int j2 = 0; j2 < 16; j2 += 2) {
      x0a = fmaf(Fr[j2],     xs_[j2],     x0a);
      x1a = fmaf(Fr[j2 + 1], xs_[j2 + 1], x1a);
    }
    #pragma unroll
    for (int c = 0; c < 8; c += 2) {
      x0a = fmaf(Fr[16 + c],     us[c],     x0a);
      x1a = fmaf(Fr[16 + c + 1], us[c + 1], x1a);
    }
    xv = x0a + x1a;
    #pragma unroll
    for (int i = 0; i < 16; ++i) xs_[i] = rdlane(xv, i);
  };

  loadFw(0, FA, cA); loadK(0, KA, kA);
  for (int t = 0; t < TT; t += 2) {
    if (t + 1 < TT) { loadFw(t + 1, FB, cB); loadK(t + 1, KB, kB); }
    fstep(t, FA, cA, KA, kA);
    if (t + 2 < TT) { loadFw(t + 2, FA, cA); loadK(t + 2, KA, kA); }
    fstep(t + 1, FB, cB, KB, kB);
  }
}
} // namespace

extern "C" void kernel_launch(void* const* d_in, const int* in_sizes, int n_in,
                              void* d_out, int out_size, void* d_ws, size_t ws_size,
                              hipStream_t stream)
{
  (void)n_in; (void)out_size; (void)d_ws; (void)ws_size;
  const float* Q  = (const float*)d_in[0];
  const float* p  = (const float*)d_in[1];
  const float* F  = (const float*)d_in[2];
  const float* c1 = (const float*)d_in[3];
  const float* x0 = (const float*)d_in[4];
  float* outp = (float*)d_out;

  const int B = in_sizes[4] / 16;   // 512
  lqr_kernel<<<B, 256, 0, stream>>>(Q, p, F, c1, x0, outp);
}

// Round 13
// 258.996 us; speedup vs baseline: 1.3743x; 1.1357x over previous
//
#include <hip/hip_runtime.h>

namespace {
constexpr int TT = 128;

__device__ __forceinline__ float rdlane(float v, int l) {
  return __int_as_float(__builtin_amdgcn_readlane(__float_as_int(v), l));
}

__device__ __forceinline__ void bsync() {
  // 256-thread barrier WITHOUT vmcnt drain: global prefetches stay in flight.
  asm volatile("s_waitcnt lgkmcnt(0)" ::: "memory");
  __builtin_amdgcn_s_barrier();
  asm volatile("" ::: "memory");
  __builtin_amdgcn_sched_barrier(0);
}

__global__ __launch_bounds__(256)
void lqr_kernel(const float* __restrict__ Qg, const float* __restrict__ pg,
                const float* __restrict__ Fg, const float* __restrict__ cg,
                const float* __restrict__ x0g, float* __restrict__ out)
{
  // Quad-XOR-swizzled tiles: element (row, n) at row*S + ((n>>2 ^ ((row>>2)&3))<<2) + (n&3)
  __shared__ __align__(16) float VT[16][20];     // plain; V columns (symmetric)
  __shared__ __align__(16) float vv[16];
  __shared__ __align__(16) float FTxd[2][25][20];// swz; rows 0..23 = F cols, 24 = c
  __shared__ __align__(16) float WTx[25][20];    // swz; rows = W^T cols, 24 = z
  __shared__ __align__(16) float QhT[25][36];    // swz; rows = Qh cols, 24 = qh
  __shared__ __align__(16) float KsT[TT][8][16]; // KsT[t][c][i] = K[c][i]
  __shared__ __align__(16) float ksv[TT][8];

  const int tid  = threadIdx.x;
  const int lane = tid & 63;
  const int wv   = tid >> 6;
  const int b    = blockIdx.x;
  const size_t bt0 = (size_t)b * TT;

  const int jl = tid & 31;   // per-lane column index (valid <25 / <24)
  const int g  = tid >> 5;   // 0..7, uniform per half-wave

  // zero ALL of VT (320 floats) + vv
  for (int e = tid; e < 320; e += 256) (&VT[0][0])[e] = 0.f;
  if (tid < 16) vv[tid] = 0.f;

  // ---- F/c staging: unit u = tid < 100 (waves 0-1 only): j = u>>2, k = u&3
  const int  fj   = tid >> 2, fk = tid & 3;
  const bool fact = (tid < 100);
  const int  fsw  = (fj < 24) ? ((fj >> 2) & 3) : 2;
  float Fr4[4] = {0.f, 0.f, 0.f, 0.f};

  auto loadF = [&](int t) {
    if (fact) {
      if (fj < 24) {
        const float* Fs = Fg + (bt0 + t) * 384 + fj;
        #pragma unroll
        for (int m = 0; m < 4; ++m) Fr4[m] = Fs[(4 * fk + m) * 24];
      } else {
        const float* cs = cg + (bt0 + t) * 16 + 4 * fk;
        #pragma unroll
        for (int m = 0; m < 4; ++m) Fr4[m] = cs[m];
      }
    }
  };
  auto commitF = [&](int buf) {
    if (fact) {
      float* dst = &FTxd[buf][fj][(fk ^ fsw) << 2];
      *(float4*)dst = make_float4(Fr4[0], Fr4[1], Fr4[2], Fr4[3]);
    }
  };

  float qreg[3] = {0.f, 0.f, 0.f}, qreg3 = 0.f;
  auto loadQ = [&](int t) {
    if (jl < 24) {
      const float* Qs = Qg + (bt0 + t) * 576;
      #pragma unroll
      for (int r = 0; r < 3; ++r) qreg[r] = Qs[(3 * g + r) * 24 + jl]; // Q sym
      if (g == 7) qreg3 = pg[(bt0 + t) * 24 + jl];
    }
  };

  // ---- prologue ----
  loadF(TT - 1);
  loadQ(TT - 1);
  commitF(1);
  loadF(TT - 2);
  bsync();

  // ===================== backward Riccati =====================
  for (int t = TT - 1; t >= 0; --t) {
    const float* Fb = &FTxd[t & 1][0][0];

    // Phase A: WTx[j][m] = sum_n V[m][n] * F[n][j]  (+v for j==24 -> z)
    float fr[16];
    if (jl < 25) {
      const int sj = (jl >> 2) & 3;
      const float* fb = Fb + jl * 20;
      #pragma unroll
      for (int q = 0; q < 4; ++q) {
        float4 v4 = *(const float4*)(fb + ((q ^ sj) << 2));
        fr[4*q+0] = v4.x; fr[4*q+1] = v4.y; fr[4*q+2] = v4.z; fr[4*q+3] = v4.w;
      }
      const int m0 = 2 * g, m1 = m0 + 1;
      float acc0 = (jl == 24) ? vv[m0] : 0.f;
      float acc1 = (jl == 24) ? vv[m1] : 0.f;
      #pragma unroll
      for (int q = 0; q < 4; ++q) {
        float4 a0 = *(const float4*)(&VT[m0][4*q]);   // broadcast per half-wave
        float4 a1 = *(const float4*)(&VT[m1][4*q]);
        acc0 = fmaf(a0.x, fr[4*q+0], acc0); acc0 = fmaf(a0.y, fr[4*q+1], acc0);
        acc0 = fmaf(a0.z, fr[4*q+2], acc0); acc0 = fmaf(a0.w, fr[4*q+3], acc0);
        acc1 = fmaf(a1.x, fr[4*q+0], acc1); acc1 = fmaf(a1.y, fr[4*q+1], acc1);
        acc1 = fmaf(a1.z, fr[4*q+2], acc1); acc1 = fmaf(a1.w, fr[4*q+3], acc1);
      }
      float* wb = &WTx[0][0] + jl * 20;
      *(float2*)(wb + ((((g >> 1) ^ sj) << 2) + (m0 & 3))) = make_float2(acc0, acc1);
    }
    bsync();

    // Phase B: QhT[c][i] = Qsrc + sum_m F[m][i] * W[m][c]   (i = jl)
    if (jl < 24) {
      #pragma unroll
      for (int r = 0; r < 3; ++r) {
        const int c = 3 * g + r;
        const int sc = (c >> 2) & 3;
        const float* wb = &WTx[0][0] + c * 20;   // broadcast per half-wave
        float acc = qreg[r];
        #pragma unroll
        for (int q = 0; q < 4; ++q) {
          float4 w4 = *(const float4*)(wb + ((q ^ sc) << 2));
          acc = fmaf(w4.x, fr[4*q+0], acc); acc = fmaf(w4.y, fr[4*q+1], acc);
          acc = fmaf(w4.z, fr[4*q+2], acc); acc = fmaf(w4.w, fr[4*q+3], acc);
        }
        float* qb = &QhT[0][0] + c * 36;
        qb[(((jl >> 2) ^ sc) << 2) + (jl & 3)] = acc;
      }
      if (g == 7) {                               // qh row (c==24), s=2
        const float* wb = &WTx[0][0] + 24 * 20;
        float acc = qreg3;
        #pragma unroll
        for (int q = 0; q < 4; ++q) {
          float4 w4 = *(const float4*)(wb + ((q ^ 2) << 2));
          acc = fmaf(w4.x, fr[4*q+0], acc); acc = fmaf(w4.y, fr[4*q+1], acc);
          acc = fmaf(w4.z, fr[4*q+2], acc); acc = fmaf(w4.w, fr[4*q+3], acc);
        }
        float* qb = &QhT[0][0] + 24 * 36;
        qb[(((jl >> 2) ^ 2) << 2) + (jl & 3)] = acc;
      }
    }
    if (t > 0) loadQ(t - 1);
    bsync();

    // GJ + gains + V-update on wave 2+(t&1); waves != GJ commit next F tile.
    // Lane layout: lanes 0..7 hold Quu cols, 8..23 hold Qux cols (x-col j at
    // lane 8+j), 24 holds qu. After 8 pivots lane 8+j: a_ = X[:,j]; lane 24: xq.
    if (wv == 2 + (t & 1)) {
      __builtin_amdgcn_s_setprio(1);
      const int cl = (lane < 25) ? lane : 0;
      const int row = (cl < 8) ? (16 + cl) : ((cl < 24) ? (cl - 8) : 24);
      const int s = (row >> 2) & 3;
      const float* base = &QhT[0][0] + row * 36;
      float a_[8];
      {
        float4 x0v = *(const float4*)(base + ((4 ^ s) << 2));
        float4 x1v = *(const float4*)(base + ((5 ^ s) << 2));
        a_[0]=x0v.x; a_[1]=x0v.y; a_[2]=x0v.z; a_[3]=x0v.w;
        a_[4]=x1v.x; a_[5]=x1v.y; a_[6]=x1v.z; a_[7]=x1v.w;
      }
      // ---- hoisted V-update reads: latency hides under the elim chain ----
      const int jv = lane & 31;
      const int ih = lane >> 5;
      const int row2 = (jv < 16) ? jv : 24;
      const int s3 = (row2 >> 2) & 3;
      const float* b2 = &QhT[0][0] + row2 * 36;
      const int q0 = 2 * ih, q1 = q0 + 1;
      float4 A0 = *(const float4*)(b2 + ((q0 ^ s3) << 2));
      float4 A1 = *(const float4*)(b2 + ((q1 ^ s3) << 2));
      float4 Bq0[8], Bq1[8];
      #pragma unroll
      for (int c = 0; c < 8; ++c) {
        const int s2 = ((16 + c) >> 2) & 3;         // compile-time 0 or 1
        const float* qb = &QhT[0][0] + (16 + c) * 36;
        Bq0[c] = *(const float4*)(qb + ((q0 ^ s2) << 2));
        Bq1[c] = *(const float4*)(qb + ((q1 ^ s2) << 2));
      }
      // ---- 8-pivot elimination (unchanged arithmetic) ----
      #pragma unroll
      for (int pp = 0; pp < 8; ++pp) {
        float f_[8];
        f_[0] = rdlane(a_[0], pp); f_[1] = rdlane(a_[1], pp);
        f_[2] = rdlane(a_[2], pp); f_[3] = rdlane(a_[3], pp);
        f_[4] = rdlane(a_[4], pp); f_[5] = rdlane(a_[5], pp);
        f_[6] = rdlane(a_[6], pp); f_[7] = rdlane(a_[7], pp);
        // Quu >= I (pivot >= ~1): raw v_rcp (~2^-22 rel err) is plenty.
        float d = __builtin_amdgcn_rcpf(f_[pp]);
        a_[pp] *= d;
        #pragma unroll
        for (int r = 0; r < 8; ++r)
          if (r != pp) a_[r] = fmaf(-f_[r], a_[pp], a_[r]);
      }
      // gains, transposed store: KsT[t][c][j] = K[c][j] = -X[c][j]
      if (lane >= 8 && lane < 24) {
        const int j = lane - 8;
        #pragma unroll
        for (int c = 0; c < 8; ++c) KsT[t][c][j] = -a_[c];
      } else if (lane == 24) {
        float4* kp = (float4*)&ksv[t][0];
        kp[0] = make_float4(-a_[0], -a_[1], -a_[2], -a_[3]);
        kp[1] = make_float4(-a_[4], -a_[5], -a_[6], -a_[7]);
      }
      // V-update spread over 64 lanes: lane (jv, ih) computes Vn[8ih..8ih+7][jv]
      // (jv==24 -> vn). X[:,jv] pulled from lane 8+jv (or 24) via ds_bpermute.
      const int sl = (jv < 16) ? (8 + jv) : 24;
      float xj[8];
      #pragma unroll
      for (int c = 0; c < 8; ++c)
        xj[c] = __int_as_float(
            __builtin_amdgcn_ds_bpermute(sl * 4, __float_as_int(a_[c])));
      if (jv < 16 || jv == 24) {
        float acc[8];
        acc[0]=A0.x; acc[1]=A0.y; acc[2]=A0.z; acc[3]=A0.w;
        acc[4]=A1.x; acc[5]=A1.y; acc[6]=A1.z; acc[7]=A1.w;
        #pragma unroll
        for (int c = 0; c < 8; ++c) {
          const float xc = xj[c];
          acc[0] = fmaf(-xc, Bq0[c].x, acc[0]); acc[1] = fmaf(-xc, Bq0[c].y, acc[1]);
          acc[2] = fmaf(-xc, Bq0[c].z, acc[2]); acc[3] = fmaf(-xc, Bq0[c].w, acc[3]);
          acc[4] = fmaf(-xc, Bq1[c].x, acc[4]); acc[5] = fmaf(-xc, Bq1[c].y, acc[5]);
          acc[6] = fmaf(-xc, Bq1[c].z, acc[6]); acc[7] = fmaf(-xc, Bq1[c].w, acc[7]);
        }
        float4* vp = (jv < 16) ? (float4*)&VT[jv][8 * ih] : (float4*)&vv[8 * ih];
        vp[0] = make_float4(acc[0], acc[1], acc[2], acc[3]);
        vp[1] = make_float4(acc[4], acc[5], acc[6], acc[7]);
      }
      __builtin_amdgcn_s_setprio(0);
    } else {
      // staging threads live ONLY in waves 0-1 (fact = tid<100), never GJ.
      if (t > 0) commitF((t - 1) & 1);
      if (t > 1) loadF(t - 2);
    }
    bsync();
  }

  // ===================== forward rollout (wave 0 only) =====================
  if (wv != 0) return;

  float xv = (lane < 16) ? x0g[(size_t)b * 16 + lane] : 0.f;
  float xs_[16];
  #pragma unroll
  for (int i = 0; i < 16; ++i) xs_[i] = rdlane(xv, i);

  float FA[24], FB[24];
  float cA = 0.f, cB = 0.f;
  float KA[16], KB[16], kA = 0.f, kB = 0.f;

  auto loadFw = [&](int t, float (&Fr)[24], float& cr) {
    if (lane < 16) {
      const float* src = Fg + (bt0 + t) * 384 + lane * 24;
      #pragma unroll
      for (int r = 0; r < 6; ++r) {
        float4 f4v = ((const float4*)src)[r];
        Fr[4*r+0] = f4v.x; Fr[4*r+1] = f4v.y; Fr[4*r+2] = f4v.z; Fr[4*r+3] = f4v.w;
      }
      cr = cg[(bt0 + t) * 16 + lane];
    }
  };
  auto loadK = [&](int t, float (&K)[16], float& kk) {
    if (lane < 8) {
      const float4* kp = (const float4*)&KsT[t][lane][0];
      float4 k0 = kp[0], k1 = kp[1], k2 = kp[2], k3 = kp[3];
      K[0]=k0.x;  K[1]=k0.y;  K[2]=k0.z;  K[3]=k0.w;
      K[4]=k1.x;  K[5]=k1.y;  K[6]=k1.z;  K[7]=k1.w;
      K[8]=k2.x;  K[9]=k2.y;  K[10]=k2.z; K[11]=k2.w;
      K[12]=k3.x; K[13]=k3.y; K[14]=k3.z; K[15]=k3.w;
      kk = ksv[t][lane];
    }
  };

  auto fstep = [&](int t, const float (&Fr)[24], float cr,
                   const float (&K)[16], float kk) {
    float uv = 0.f;
    if (lane < 8) {
      float u0 = kk, u1 = 0.f;
      #pragma unroll
      for (int i = 0; i < 16; i += 2) {
        u0 = fmaf(K[i],     xs_[i],     u0);
        u1 = fmaf(K[i + 1], xs_[i + 1], u1);
      }
      uv = u0 + u1;
    }
    float us[8];
    #pragma unroll
    for (int c = 0; c < 8; ++c) us[c] = rdlane(uv, c);
    float* o = out + (bt0 + t) * 24;
    if (lane < 16) o[lane] = xv;
    if (lane < 8)  o[16 + lane] = uv;
    float x0a = cr, x1a = 0.f;
    #pragma unroll
    for (int j2 = 0; j2 < 16; j2 += 2) {
      x0a = fmaf(Fr[j2],     xs_[j2],     x0a);
      x1a = fmaf(Fr[j2 + 1], xs_[j2 + 1], x1a);
    }
    #pragma unroll
    for (int c = 0; c < 8; c += 2) {
      x0a = fmaf(Fr[16 + c],     us[c],     x0a);
      x1a = fmaf(Fr[16 + c + 1], us[c + 1], x1a);
    }
    xv = x0a + x1a;
    #pragma unroll
    for (int i = 0; i < 16; ++i) xs_[i] = rdlane(xv, i);
  };

  loadFw(0, FA, cA); loadK(0, KA, kA);
  for (int t = 0; t < TT; t += 2) {
    if (t + 1 < TT) { loadFw(t + 1, FB, cB); loadK(t + 1, KB, kB); }
    fstep(t, FA, cA, KA, kA);
    if (t + 2 < TT) { loadFw(t + 2, FA, cA); loadK(t + 2, KA, kA); }
    fstep(t + 1, FB, cB, KB, kB);
  }
}
} // namespace

extern "C" void kernel_launch(void* const* d_in, const int* in_sizes, int n_in,
                              void* d_out, int out_size, void* d_ws, size_t ws_size,
                              hipStream_t stream)
{
  (void)n_in; (void)out_size; (void)d_ws; (void)ws_size;
  const float* Q  = (const float*)d_in[0];
  const float* p  = (const float*)d_in[1];
  const float* F  = (const float*)d_in[2];
  const float* c1 = (const float*)d_in[3];
  const float* x0 = (const float*)d_in[4];
  float* outp = (float*)d_out;

  const int B = in_sizes[4] / 16;   // 512
  lqr_kernel<<<B, 256, 0, stream>>>(Q, p, F, c1, x0, outp);
}